// Round 4
// baseline (447.607 us; speedup 1.0000x reference)
//
#include <hip/hip_runtime.h>

// LSTM B=1024,T=512,F=40,H=50. r7/r10 = 267/271us, latency-bound:
// ~1270cy/step at 25% MFMA / 22% VALU / 23% occupancy (2 blocks/CU, 2
// waves/SIMD). The two chains per SIMD phase-lock at barriers and fail to
// fill each other's stalls. r11: kMB=1, grid=1024, launch_bounds(256,4)
// -> 4 blocks/CU = 4 independent serial chains per SIMD. Per-chain work
// unchanged (B columns were mostly pad); total issue per CU doubles but
// pipes are <26% busy. VGPR=68 <= 128 keeps 4 waves/SIMD; LDS 36KB/CU.
//
// GEMM per step: G^T[208,16] = W'[208,96] @ [x|h]^T[96,16], rows' =
// 4*unit+gate (i,f,g,o interleaved), 13 M-tiles split 3/3/3/4 over 4 waves,
// 3 K-chunks (K=96: x 0..39 | h 40..89 | pad). D lane (m16,q) holds gates
// r=0..3 of unit 4*tile+q, batch col m16 (only m16<1 real). Pointwise on
// 50 dense lanes (wave 0), x stagers in wave 2, distance-2 prefetch.
// Raw "lgkmcnt(0); s_barrier" barriers (r10: neutral but never worse).

constexpr int kT   = 512;
constexpr int kF   = 40;
constexpr int kH   = 50;
constexpr int kMB  = 1;      // real batches per block
constexpr int kRowS = 104;   // combined panel row stride in shorts (208 B)
constexpr int kGRow = 208;   // sh_g row stride in dwords (13 tiles * 16)

typedef __attribute__((ext_vector_type(8))) short bf16x8;
typedef __attribute__((ext_vector_type(4))) float f32x4;

__device__ __forceinline__ unsigned short f2bf(float f) {
    union { float f; unsigned u; } v; v.f = f;
    return (unsigned short)((v.u + 0x7FFFu + ((v.u >> 16) & 1u)) >> 16);
}
__device__ __forceinline__ float fast_sigmoid(float v) {
    return __builtin_amdgcn_rcpf(1.f + __expf(-v));
}
__device__ __forceinline__ float fast_tanh(float v) {
    return 1.f - 2.f * __builtin_amdgcn_rcpf(__expf(2.f * v) + 1.f);
}

__global__ __launch_bounds__(256, 4)
void lstm_mfma_4cu(
    const float* __restrict__ x,      // [B,T,F]
    const float* __restrict__ W_ih,   // [4H,F]
    const float* __restrict__ W_hh,   // [4H,H]
    const float* __restrict__ b_ih,   // [4H]
    const float* __restrict__ b_hh,   // [4H]
    const float* __restrict__ W1,     // [10,H]
    const float* __restrict__ b1,     // [10]
    const float* __restrict__ W2,     // [1,10]
    const float* __restrict__ b2,     // [1]
    float* __restrict__ out)          // [B]
{
    const int tid  = threadIdx.x;
    const int lane = tid & 63;
    const int wave = tid >> 6;
    const int bb   = blockIdx.x;
    const int m16  = lane & 15;    // D col = batch
    const int q    = lane >> 4;    // quad

    __shared__ short sh_comb[2][16][kRowS];  // [x(0..39)|h(40..89)|pad] bf16
    __shared__ float sh_g[kMB][kGRow];       // gate pre-acts, rows' = 4u+r
    __shared__ float sh_hf[kMB][kH + 2];     // final h fp32
    __shared__ float sh_head[kMB][10];

    const int t0 = (wave == 3) ? 9 : wave * 3;   // first tile of this wave
    const int NT = (wave == 3) ? 4 : 3;          // tiles 3/3/3/4 = 13

    // zero the combined panels (pads + batch cols 1..15 stay 0 forever)
    { int* z = (int*)sh_comb; for (int i = tid; i < 1664; i += 256) z[i] = 0; }

    // ---- A-frag weights (registers) + bias for C operand ----
    bf16x8 wa[4][3];
    float  bias[4][4];
    const int uA = m16 >> 2, gA = m16 & 3;
#pragma unroll
    for (int i = 0; i < 4; ++i) {
        const int tl = t0 + i;
        const int unitA = 4 * tl + uA;
        const bool live = (i < NT) && (unitA < kH);
        const int orow = live ? (unitA + 50 * gA) : 0;
#pragma unroll
        for (int kk = 0; kk < 3; ++kk) {
            bf16x8 v;
#pragma unroll
            for (int j = 0; j < 8; ++j) {
                const int k = kk * 32 + q * 8 + j;
                float wv = 0.f;
                if (live) {
                    if (k < kF)           wv = W_ih[orow * kF + k];
                    else if (k < kF + kH) wv = W_hh[orow * kH + (k - kF)];
                }
                v[j] = (short)f2bf(wv);
            }
            wa[i][kk] = v;
        }
        const int uD = 4 * tl + q;
#pragma unroll
        for (int r = 0; r < 4; ++r)
            bias[i][r] = (i < NT && uD < kH)
                       ? (b_ih[uD + 50 * r] + b_hh[uD + 50 * r]) : 0.f;
    }

    // ---- dense pointwise owners: tid<50 -> (batch pm=0, unit pu) ----
    const bool pw = (tid < kMB * kH);
    const int  pm = pw ? (tid / kH) : 0;
    const int  pu = pw ? (tid % kH) : 0;
    float c     = (pw && pu == 0) ? 1.f : 0.f;   // c0[:,0] = 1
    float lasth = 0.f;

    // ---- x stagers: wave 2 lanes 0..19 own (batch xm=0, float2 chunk xd) --
    const bool xs = (tid >= 128 && tid < 128 + kMB * 20);
    const int  xi = xs ? (tid - 128) : 0;
    const int  xm = xi / 20, xd = xi % 20;
    const float* xrow = x + ((size_t)(bb * kMB + xm) * kT) * kF + 2 * xd;

    float2 pa = {0.f, 0.f}, pb = {0.f, 0.f};
    __syncthreads();                              // zero-init done
    if (xs) {
        float2 v0 = *(const float2*)xrow;         // x_0
        unsigned pk = (unsigned)f2bf(v0.x) | ((unsigned)f2bf(v0.y) << 16);
        *(unsigned*)&sh_comb[0][xm][2 * xd] = pk;
        pa = *(const float2*)(xrow + (size_t)1 * kF);   // x_1 (used t=0)
        pb = *(const float2*)(xrow + (size_t)2 * kF);   // x_2 (used t=1)
    }
    __syncthreads();

    // ---- one step; CUR = t&1 compile-time via 2-phase unroll ----
    auto step = [&](int t, int CUR, float2& pf) {
        const short* rowp = &sh_comb[CUR][m16][0];
        bf16x8 bv0 = *(const bf16x8*)(rowp +      q * 8);   // k  0..31
        bf16x8 bv1 = *(const bf16x8*)(rowp + 32 + q * 8);   // k 32..63
        bf16x8 bv2 = *(const bf16x8*)(rowp + 64 + q * 8);   // k 64..95
#pragma unroll
        for (int i = 0; i < 4; ++i) {
            if (i < NT) {                                   // wave-uniform
                f32x4 d;
                d[0] = bias[i][0]; d[1] = bias[i][1];
                d[2] = bias[i][2]; d[3] = bias[i][3];
                d = __builtin_amdgcn_mfma_f32_16x16x32_bf16(wa[i][0], bv0, d, 0, 0, 0);
                d = __builtin_amdgcn_mfma_f32_16x16x32_bf16(wa[i][1], bv1, d, 0, 0, 0);
                d = __builtin_amdgcn_mfma_f32_16x16x32_bf16(wa[i][2], bv2, d, 0, 0, 0);
                if (m16 < kMB)                              // 1 real col only
                    *(f32x4*)&sh_g[m16][16 * (t0 + i) + 4 * q] = d;
            }
        }
        // barrier A: sh_g ready. LDS-only drain; keep x prefetch in flight.
        asm volatile("s_waitcnt lgkmcnt(0)\n\ts_barrier" ::: "memory");

        short* nbuf = &sh_comb[CUR ^ 1][0][0];
        if (pw) {
            f32x4 g = *(const f32x4*)&sh_g[pm][4 * pu];     // i,f,g,o of unit pu
            float i_s = fast_sigmoid(g[0]);
            float f_s = fast_sigmoid(g[1]);
            float g_t = fast_tanh   (g[2]);
            float o_s = fast_sigmoid(g[3]);
            c = fmaf(f_s, c, i_s * g_t);
            lasth = o_s * fast_tanh(c);
            if (t + 1 < kT)
                nbuf[pm * kRowS + kF + pu] = (short)f2bf(lasth);
        } else if (xs) {
            if (t + 1 < kT) {
                unsigned pk = (unsigned)f2bf(pf.x) | ((unsigned)f2bf(pf.y) << 16);
                *(unsigned*)&nbuf[xm * kRowS + 2 * xd] = pk;
            }
            if (t + 3 < kT)                                  // distance-2 prefetch
                pf = *(const float2*)(xrow + (size_t)(t + 3) * kF);
        }
        // barrier B: next panel ready.
        asm volatile("s_waitcnt lgkmcnt(0)\n\ts_barrier" ::: "memory");
    };

    for (int t = 0; t < kT; t += 2) {
        step(t,     0, pa);
        step(t + 1, 1, pb);
    }

    // ---- head: relu(h @ W1.T + b1) @ W2.T + b2 + x[b, T-1, 0] ----
    if (pw) sh_hf[pm][pu] = lasth;
    __syncthreads();
    if (tid < kMB * 10) {
        const int m = tid / 10, j = tid % 10;
        float acc = b1[j];
#pragma unroll
        for (int k = 0; k < kH; ++k) acc = fmaf(sh_hf[m][k], W1[j * kH + k], acc);
        sh_head[m][j] = fmaxf(acc, 0.f);
    }
    __syncthreads();
    if (tid < kMB) {
        float acc = b2[0];
#pragma unroll
        for (int j2 = 0; j2 < 10; ++j2) acc = fmaf(sh_head[tid][j2], W2[j2], acc);
        const int bidx = bb * kMB + tid;
        out[bidx] = acc + x[((size_t)bidx * kT + (kT - 1)) * kF];
    }
}

extern "C" void kernel_launch(void* const* d_in, const int* in_sizes, int n_in,
                              void* d_out, int out_size, void* d_ws, size_t ws_size,
                              hipStream_t stream) {
    const float* x    = (const float*)d_in[0];
    const float* W_ih = (const float*)d_in[1];
    const float* W_hh = (const float*)d_in[2];
    const float* b_ih = (const float*)d_in[3];
    const float* b_hh = (const float*)d_in[4];
    const float* W1   = (const float*)d_in[5];
    const float* b1   = (const float*)d_in[6];
    const float* W2   = (const float*)d_in[7];
    const float* b2   = (const float*)d_in[8];
    float* out = (float*)d_out;

    lstm_mfma_4cu<<<dim3(1024 / kMB), dim3(256), 0, stream>>>(
        x, W_ih, W_hh, b_ih, b_hh, W1, b1, W2, b2, out);
}

// Round 6
// 376.530 us; speedup vs baseline: 1.1888x; 1.1888x over previous
//
#include <hip/hip_runtime.h>

// LSTM B=1024,T=512,F=40,H=50. r7/r10 = 267/271us (2 barriers + sh_g LDS
// roundtrip per step). r11 (4 blocks/CU) = 372us: replicating the padded
// GEMM doubles issue without adding useful parallelism. r12 restructures
// the chain itself (resubmit: r5 bench was an infra failure, kernel audited
// clean -- bounds, barrier uniformity, dbuf ordering, frag maps).
//  * SWAPPED MFMA OPERANDS: mfma(panel, W) instead of mfma(W, panel).
//    A/B frag lane maps are symmetric (outer idx = lane&15, k=(lane>>4)*8+j),
//    so this transposes D for free: D[row=batch=4q+reg][col=w-row=m16].
//  * GATE-PER-TILE weight permutation: wave w's 4 tiles = gates i,f,g,o of
//    units 16w+m16. Lane (m16,q=0) then holds ALL FOUR gates of unit
//    u=16w+m16 for batches 0,1 in dd[0..3][0..1] -> pointwise fully
//    in-register, no exchange, no divergence (gate index = register index).
//    c,h persist in registers; h written straight into the next panel.
//  * ONE barrier per step (end-of-step barrier separates step t's panel
//    reads from step t+1's writes on the double buffer). sh_g + barrier A
//    + its conflicted read are deleted (~350-450cy off the chain).
//  16 tiles vs 13, uniform 4/wave (old critical wave had 4 already).
//  Transc: 20 instrs/wave (3 sigmoid + 2 tanh, 2 batches), 2-pair-deep chain.
//  x stagers: lanes 48..57 of each wave (q=3, never pointwise-real),
//  distance-2 register prefetch, raw lgkmcnt-only barriers.

constexpr int kT    = 512;
constexpr int kF    = 40;
constexpr int kH    = 50;
constexpr int kMB   = 2;      // real batches per block
constexpr int kRowS = 104;    // combined panel row stride in shorts (208 B)

typedef __attribute__((ext_vector_type(8))) short bf16x8;
typedef __attribute__((ext_vector_type(4))) float f32x4;

__device__ __forceinline__ unsigned short f2bf(float f) {
    union { float f; unsigned u; } v; v.f = f;
    return (unsigned short)((v.u + 0x7FFFu + ((v.u >> 16) & 1u)) >> 16);
}
__device__ __forceinline__ float fast_sigmoid(float v) {
    return __builtin_amdgcn_rcpf(1.f + __expf(-v));
}
__device__ __forceinline__ float fast_tanh(float v) {
    return 1.f - 2.f * __builtin_amdgcn_rcpf(__expf(2.f * v) + 1.f);
}

__global__ __launch_bounds__(256, 2)
void lstm_mfma_swapped(
    const float* __restrict__ x,      // [B,T,F]
    const float* __restrict__ W_ih,   // [4H,F]
    const float* __restrict__ W_hh,   // [4H,H]
    const float* __restrict__ b_ih,   // [4H]
    const float* __restrict__ b_hh,   // [4H]
    const float* __restrict__ W1,     // [10,H]
    const float* __restrict__ b1,     // [10]
    const float* __restrict__ W2,     // [1,10]
    const float* __restrict__ b2,     // [1]
    float* __restrict__ out)          // [B]
{
    const int tid  = threadIdx.x;
    const int lane = tid & 63;
    const int wave = tid >> 6;
    const int bb   = blockIdx.x;
    const int m16  = lane & 15;    // D col = tile-local weight row / owned unit
    const int q    = lane >> 4;    // k-quad; D rows 4q..4q+3 = batches

    __shared__ short sh_comb[2][16][kRowS];  // [x(0..39)|h(40..89)|pad] bf16
    __shared__ float sh_hf[kMB][kH + 2];     // final h fp32
    __shared__ float sh_head[kMB][10];

    const int u = 16 * wave + m16;           // owned unit (cols 50..63 dead)
    const bool ulive = (u < kH);

    // zero the combined panels (pads + batch rows 2..15 stay 0 forever)
    { int* z = (int*)sh_comb; for (int i = tid; i < 1664; i += 256) z[i] = 0; }

    // ---- B-frag weights (registers): tile r = gate r of unit u ----
    // B[k][col=m16] = W'[50r + u][k], frag elem jj of chunk kk: k=32kk+8q+jj
    bf16x8 wb[4][3];
    float  biasv[4];
#pragma unroll
    for (int r = 0; r < 4; ++r) {
        const int nrow = ulive ? (50 * r + u) : 0;
#pragma unroll
        for (int kk = 0; kk < 3; ++kk) {
            bf16x8 v;
#pragma unroll
            for (int j = 0; j < 8; ++j) {
                const int k = kk * 32 + q * 8 + j;
                float wv = 0.f;
                if (ulive) {
                    if (k < kF)           wv = W_ih[nrow * kF + k];
                    else if (k < kF + kH) wv = W_hh[nrow * kH + (k - kF)];
                }
                v[j] = (short)f2bf(wv);
            }
            wb[r][kk] = v;
        }
        biasv[r] = ulive ? (b_ih[50 * r + u] + b_hh[50 * r + u]) : 0.f;
    }

    // ---- cell state in registers (q==0 lanes real; others junk, harmless)
    float c0 = (u == 0) ? 1.f : 0.f;   // c0[:,0] = 1 (both batches)
    float c1 = c0;
    float h0 = 0.f, h1 = 0.f;

    // ---- x stagers: lanes 48..57 (q=3) of each wave ----
    const bool xs = (lane >= 48 && lane < 58);
    const int  fid = xs ? (wave * 10 + (lane - 48)) : 0;   // 0..39
    const int  xm = fid / 20, xd = fid % 20;
    const float* xrow = x + ((size_t)(bb * kMB + xm) * kT) * kF + 2 * xd;

    float2 pa = {0.f, 0.f}, pb = {0.f, 0.f};
    __syncthreads();                              // zero-init done
    if (xs) {
        float2 v0 = *(const float2*)xrow;         // x_0
        unsigned pk = (unsigned)f2bf(v0.x) | ((unsigned)f2bf(v0.y) << 16);
        *(unsigned*)&sh_comb[0][xm][2 * xd] = pk;
        pa = *(const float2*)(xrow + (size_t)1 * kF);   // x_1 (used t=0)
        pb = *(const float2*)(xrow + (size_t)2 * kF);   // x_2 (used t=1)
    }
    __syncthreads();

    // ---- one step; CUR = t&1 compile-time via 2-phase unroll ----
    auto step = [&](int t, int CUR, float2& pf) {
        const short* rowp = &sh_comb[CUR][m16][0];
        bf16x8 bv0 = *(const bf16x8*)(rowp +      q * 8);   // k  0..31
        bf16x8 bv1 = *(const bf16x8*)(rowp + 32 + q * 8);   // k 32..63
        bf16x8 bv2 = *(const bf16x8*)(rowp + 64 + q * 8);   // k 64..95
        f32x4 dd[4];
#pragma unroll
        for (int r = 0; r < 4; ++r) {
            f32x4 d;
            d[0] = biasv[r]; d[1] = biasv[r]; d[2] = biasv[r]; d[3] = biasv[r];
            // swapped operands: A = panel rows (batches), B = weights
            d = __builtin_amdgcn_mfma_f32_16x16x32_bf16(bv0, wb[r][0], d, 0, 0, 0);
            d = __builtin_amdgcn_mfma_f32_16x16x32_bf16(bv1, wb[r][1], d, 0, 0, 0);
            d = __builtin_amdgcn_mfma_f32_16x16x32_bf16(bv2, wb[r][2], d, 0, 0, 0);
            dd[r] = d;
        }
        short* nbuf = &sh_comb[CUR ^ 1][0][0];
        if (xs) {                                           // issue early
            if (t + 1 < kT) {
                unsigned pk = (unsigned)f2bf(pf.x) | ((unsigned)f2bf(pf.y) << 16);
                *(unsigned*)&nbuf[xm * kRowS + 2 * xd] = pk;
            }
            if (t + 3 < kT)                                 // distance-2 prefetch
                pf = *(const float2*)(xrow + (size_t)(t + 3) * kF);
        }
        // pointwise, fully in-register; uniform on all lanes (q==0 real)
        {
            float i_s = fast_sigmoid(dd[0][0]);
            float f_s = fast_sigmoid(dd[1][0]);
            float g_t = fast_tanh   (dd[2][0]);
            float o_s = fast_sigmoid(dd[3][0]);
            c0 = fmaf(f_s, c0, i_s * g_t);
            h0 = o_s * fast_tanh(c0);
        }
        {
            float i_s = fast_sigmoid(dd[0][1]);
            float f_s = fast_sigmoid(dd[1][1]);
            float g_t = fast_tanh   (dd[2][1]);
            float o_s = fast_sigmoid(dd[3][1]);
            c1 = fmaf(f_s, c1, i_s * g_t);
            h1 = o_s * fast_tanh(c1);
        }
        if (q == 0 && ulive && t + 1 < kT) {
            nbuf[0 * kRowS + kF + u] = (short)f2bf(h0);
            nbuf[1 * kRowS + kF + u] = (short)f2bf(h1);
        }
        // single barrier: separates this step's panel reads/writes from the
        // next step's. LDS-only drain; x prefetch stays in flight.
        asm volatile("s_waitcnt lgkmcnt(0)\n\ts_barrier" ::: "memory");
    };

    for (int t = 0; t < kT; t += 2) {
        step(t,     0, pa);
        step(t + 1, 1, pb);
    }

    // ---- head: relu(h @ W1.T + b1) @ W2.T + b2 + x[b, T-1, 0] ----
    if (q == 0 && ulive) { sh_hf[0][u] = h0; sh_hf[1][u] = h1; }
    __syncthreads();
    if (tid < kMB * 10) {
        const int m = tid / 10, j = tid % 10;
        float acc = b1[j];
#pragma unroll
        for (int k = 0; k < kH; ++k) acc = fmaf(sh_hf[m][k], W1[j * kH + k], acc);
        sh_head[m][j] = fmaxf(acc, 0.f);
    }
    __syncthreads();
    if (tid < kMB) {
        float acc = b2[0];
#pragma unroll
        for (int j2 = 0; j2 < 10; ++j2) acc = fmaf(sh_head[tid][j2], W2[j2], acc);
        const int bidx = bb * kMB + tid;
        out[bidx] = acc + x[((size_t)bidx * kT + (kT - 1)) * kF];
    }
}

extern "C" void kernel_launch(void* const* d_in, const int* in_sizes, int n_in,
                              void* d_out, int out_size, void* d_ws, size_t ws_size,
                              hipStream_t stream) {
    const float* x    = (const float*)d_in[0];
    const float* W_ih = (const float*)d_in[1];
    const float* W_hh = (const float*)d_in[2];
    const float* b_ih = (const float*)d_in[3];
    const float* b_hh = (const float*)d_in[4];
    const float* W1   = (const float*)d_in[5];
    const float* b1   = (const float*)d_in[6];
    const float* W2   = (const float*)d_in[7];
    const float* b2   = (const float*)d_in[8];
    float* out = (float*)d_out;

    lstm_mfma_swapped<<<dim3(1024 / kMB), dim3(256), 0, stream>>>(
        x, W_ih, W_hh, b_ih, b_hh, W1, b1, W2, b2, out);
}